// Round 5
// baseline (571.985 us; speedup 1.0000x reference)
//
#include <hip/hip_runtime.h>
#include <hip/hip_bf16.h>

#define IN_CH 512
#define OUT_CH 512
#define W_DIM 512
#define BATCH 16
#define HWDIM 64
#define PADW 66

static constexpr float CONV_COEF = 0.014731391274719739f; // 1/sqrt(9*512)
static constexpr float FC_COEF   = 0.044194173824159216f; // 1/sqrt(512)

typedef __bf16 bf16x8 __attribute__((ext_vector_type(8)));
typedef float  f32x16 __attribute__((ext_vector_type(16)));

typedef __attribute__((address_space(1))) void gvoid;
typedef __attribute__((address_space(3))) void lvoid;

__device__ __forceinline__ void async_cp16(const void* g, void* l) {
    __builtin_amdgcn_global_load_lds((gvoid*)g, (lvoid*)l, 16, 0, 0);
}

__device__ __forceinline__ ushort f2bf(float f) {
    union { float f; unsigned u; } un; un.f = f;
    unsigned u = un.u;
    return (ushort)((u + 0x7fffu + ((u >> 16) & 1u)) >> 16);
}

// ---------------------------------------------------------------------------
// k_pre1: fused {style, a2, halo, wT} — all mutually independent; one launch.
//   blocks [0,32)      style: s[b,i] = (wl[b,:]·fcw[:,i])*FC_COEF + fcb[i] + 1
//   blocks [32,1056)   a2[n] = sum_kk w[kk][n]^2
//   blocks [1056,2096) halo: zero the pad ring of xs
//   blocks [2096,4400) wT[kk][out][in] = bf16(w[kk][in][out])
// ---------------------------------------------------------------------------
__global__ __launch_bounds__(256) void k_pre1(
    const float* __restrict__ wl, const float* __restrict__ fcw,
    const float* __restrict__ fcb, float* __restrict__ s,
    const float* __restrict__ w, float* __restrict__ a2,
    ushort* __restrict__ xs, ushort* __restrict__ wT) {
    const int tid = threadIdx.x;
    const int blk = blockIdx.x;

    if (blk < 32) {                     // ---- style
        __shared__ float lw[W_DIM];
        int b = blk >> 1;
        int i = (blk & 1) * 256 + tid;
        for (int j = tid; j < W_DIM; j += 256) lw[j] = wl[b * W_DIM + j];
        __syncthreads();
        float acc = 0.f;
#pragma unroll 8
        for (int j = 0; j < W_DIM; ++j) acc += lw[j] * fcw[(size_t)j * IN_CH + i];
        s[b * IN_CH + i] = acc * FC_COEF + fcb[i] + 1.0f;
    } else if (blk < 1056) {            // ---- a2
        int n = (blk - 32) * 256 + tid;
        float sum = 0.f;
#pragma unroll
        for (int kk = 0; kk < 9; ++kk) {
            float v = w[(size_t)kk * (IN_CH * OUT_CH) + n];
            sum += v * v;
        }
        a2[n] = sum;
    } else if (blk < 2096) {            // ---- halo
        int idx = blk - 1056;           // 0..1039
        int b = idx / 65;
        int pidx = (idx % 65) * 4 + (tid >> 6);  // 0..259
        int ch = tid & 63;
        int h, wq;
        if (pidx < 66)       { h = 0;          wq = pidx; }
        else if (pidx < 132) { h = 65;         wq = pidx - 66; }
        else if (pidx < 196) { h = pidx - 131; wq = 0; }
        else                 { h = pidx - 195; wq = 65; }
        size_t base = (((size_t)(b * PADW + h)) * PADW + wq) * IN_CH + ch * 8;
        uint4 z = {0u, 0u, 0u, 0u};
        *(uint4*)(xs + base) = z;
    } else {                            // ---- wT transpose
        __shared__ float tile[32][33];
        int idx = blk - 2096;           // 0..2303
        int kk = idx >> 8;              // 0..8
        int rem = idx & 255;
        int o0 = (rem & 15) * 32;
        int i0 = (rem >> 4) * 32;
        int tx = tid & 31, ty = tid >> 5;  // 32 x 8
        const float* src = w + (size_t)kk * IN_CH * OUT_CH;
        ushort* dst = wT + (size_t)kk * IN_CH * OUT_CH;
#pragma unroll
        for (int rr = 0; rr < 32; rr += 8)
            tile[ty + rr][tx] = src[(size_t)(i0 + ty + rr) * OUT_CH + o0 + tx];
        __syncthreads();
#pragma unroll
        for (int rr = 0; rr < 32; rr += 8)
            dst[(size_t)(o0 + ty + rr) * IN_CH + i0 + tx] = f2bf(tile[tx][ty + rr]);
    }
}

// ---------------------------------------------------------------------------
// k_pre2: fused {xs, dmod} — both depend only on k_pre1 outputs.
//   blocks [0,32768)     xs[b][h+1][w+1][c] = bf16(x * s)   (8.39M float4s)
//   blocks [32768,32800) dmod[b,o] = rsqrt(coef^2 * sum a2[i,o]*s[b,i]^2 + 1e-8)
// ---------------------------------------------------------------------------
__global__ __launch_bounds__(256) void k_pre2(
    const float* __restrict__ x, const float* __restrict__ s,
    ushort* __restrict__ xs, const float* __restrict__ a2,
    float* __restrict__ dmod) {
    const int tid = threadIdx.x;
    const int blk = blockIdx.x;

    if (blk < 32768) {                  // ---- xs modulate+cast
        int t = blk * 256 + tid;
        int pix = t >> 7;
        int c = (t & 127) << 2;
        int b = pix >> 12;
        int hw = pix & 4095;
        int h = hw >> 6, wq = hw & 63;
        float4 xv = ((const float4*)x)[t];
        float4 sv = ((const float4*)(s + b * IN_CH))[t & 127];
        ushort4 o;
        o.x = f2bf(xv.x * sv.x);
        o.y = f2bf(xv.y * sv.y);
        o.z = f2bf(xv.z * sv.z);
        o.w = f2bf(xv.w * sv.w);
        size_t dst = (((size_t)(b * PADW + h + 1)) * PADW + (wq + 1)) * IN_CH + c;
        *(ushort4*)(xs + dst) = o;
    } else {                            // ---- dmod
        __shared__ float s2[IN_CH];
        int sb = blk - 32768;           // 0..31
        int b = sb >> 1;
        int o = (sb & 1) * 256 + tid;
        for (int i = tid; i < IN_CH; i += 256) {
            float v = s[b * IN_CH + i];
            s2[i] = v * v;
        }
        __syncthreads();
        float acc = 0.f;
#pragma unroll 8
        for (int i = 0; i < IN_CH; ++i) acc += s2[i] * a2[(size_t)i * OUT_CH + o];
        dmod[b * OUT_CH + o] = rsqrtf(acc * CONV_COEF * CONV_COEF + 1e-8f);
    }
}

// ---------------------------------------------------------------------------
// Implicit-GEMM conv, 256x256 tile, 32x32x16 MFMA (2382-2495 TF ceiling vs
// 2075 for 16x16x32 — -17% matrix-pipe time at identical LDS traffic).
//   M=65536, N=512, K=4608. BM=BN=256, BK=64, 8 waves (2M x 4N), 128 KiB LDS.
//   Per-wave output 128x64 = 4x2 tiles of 32x32; acc = 8 x f32x16 = 128 VGPR.
//   Per K-step: 4 phases (one k-slice of 16 each): {6 ds_read_b128,
//   stage (phases 0-1), bar, setprio, 8 MFMA, setprio, bar}. vmcnt(0) only
//   at end of phase 3 (~2 phases after issue — drained, effectively free).
// ---------------------------------------------------------------------------

__device__ __forceinline__ int aoff_of(int t) {
    int kk = t >> 3;
    int c0 = (t & 7) << 6;
    int kh = (kk >= 6) ? 2 : ((kk >= 3) ? 1 : 0);
    int kw = kk - kh * 3;
    return (kh * PADW + kw) * IN_CH + c0;
}

__device__ __forceinline__ int boff_of(int t) {
    int kk = t >> 3;
    int c0 = (t & 7) << 6;
    return kk * (IN_CH * OUT_CH) + c0;
}

__device__ __forceinline__ void bar() {
    asm volatile("" ::: "memory");
    __builtin_amdgcn_s_barrier();
    asm volatile("" ::: "memory");
}

// one K-step = 4 k-slice phases; reads from (aBase,bBase); stages next tile
__device__ __forceinline__ void step32(
    const ushort* __restrict__ aBase, const ushort* __restrict__ bBase,
    int q2, int lane7,
    const ushort* __restrict__ gA, const ushort* __restrict__ gB,
    ushort* __restrict__ dA, ushort* __restrict__ dB,
    bool doStage, f32x16 (&acc)[4][2])
{
#pragma unroll
    for (int sl = 0; sl < 4; ++sl) {
        const int pc = ((2 * sl + q2) ^ lane7) * 8;
        bf16x8 av[4], bv[2];
#pragma unroll
        for (int j = 0; j < 2; ++j) bv[j] = *(const bf16x8*)(bBase + j * 2048 + pc);
#pragma unroll
        for (int i = 0; i < 4; ++i) av[i] = *(const bf16x8*)(aBase + i * 2048 + pc);
        if (sl == 0 && doStage) {
#pragma unroll
            for (int i = 0; i < 4; ++i)
                async_cp16(gA + i * (PADW * IN_CH), dA + i * 4096);
        }
        if (sl == 1 && doStage) {
#pragma unroll
            for (int i = 0; i < 4; ++i)
                async_cp16(gB + i * (64 * IN_CH), dB + i * 4096);
        }
        bar();
        __builtin_amdgcn_s_setprio(1);
#pragma unroll
        for (int i = 0; i < 4; ++i)
#pragma unroll
            for (int j = 0; j < 2; ++j)
                acc[i][j] = __builtin_amdgcn_mfma_f32_32x32x16_bf16(
                    av[i], bv[j], acc[i][j], 0, 0, 0);
        __builtin_amdgcn_s_setprio(0);
        if (sl == 3) asm volatile("s_waitcnt vmcnt(0)" ::: "memory");
        bar();
    }
}

__global__ __launch_bounds__(512, 2) void k_conv(
    const ushort* __restrict__ xs, const ushort* __restrict__ wT,
    const float* __restrict__ dmod, const float* __restrict__ bias,
    float* __restrict__ out) {
    __shared__ __align__(16) ushort smem[4][16384];  // A0,B0,A1,B1 — 128 KiB

    const int tid = threadIdx.x;
    const int wave = tid >> 6;
    const int lane = tid & 63;
    const int srow = tid >> 3;                 // staging row within 64-row slab
    const int lc = (tid & 7) ^ (srow & 7);     // pre-swizzled logical k-chunk

    // XCD swizzle (512 blocks, 512%8==0 → bijective)
    const int wg = (blockIdx.x & 7) * 64 + (blockIdx.x >> 3);
    const int nt = wg >> 8;                    // 0..1
    const int mt = wg & 255;                   // 0..255
    const int b  = mt >> 4;
    const int h0 = (mt & 15) << 2;             // 4 h-rows per M-tile
    const int n0 = nt << 8;

    const ushort* gA0 = xs + (((size_t)(b * PADW + h0)) * PADW + srow) * IN_CH + lc * 8;
    const ushort* gB0 = wT + ((size_t)(n0 + srow)) * IN_CH + lc * 8;

    ushort* dA[2] = { &smem[0][wave * 512], &smem[2][wave * 512] };
    ushort* dB[2] = { &smem[1][wave * 512], &smem[3][wave * 512] };

    const int lane31 = lane & 31;
    const int q2 = lane >> 5;                  // k-half within slice of 16
    const int lane7 = lane & 7;
    const int wm = wave >> 2;                  // 0..1 (M half)
    const int wn = wave & 3;                   // 0..3 (N quarter)

    // frag rows: A row = wm*128 + i*32 + lane31; B row = wn*64 + j*32 + lane31
    // row&7 == lane7 for all fragments (tile offsets are multiples of 32)
    const ushort* aBase[2] = {
        &smem[0][(wm * 128 + lane31) * 64],
        &smem[2][(wm * 128 + lane31) * 64],
    };
    const ushort* bBase[2] = {
        &smem[1][(wn * 64 + lane31) * 64],
        &smem[3][(wn * 64 + lane31) * 64],
    };

    f32x16 acc[4][2];
#pragma unroll
    for (int i = 0; i < 4; ++i)
#pragma unroll
        for (int j = 0; j < 2; ++j)
#pragma unroll
            for (int e = 0; e < 16; ++e) acc[i][j][e] = 0.f;

    // prologue: stage t=0 into buf0
#pragma unroll
    for (int i = 0; i < 4; ++i) {
        async_cp16(gA0 + aoff_of(0) + i * (PADW * IN_CH), dA[0] + i * 4096);
        async_cp16(gB0 + boff_of(0) + i * (64 * IN_CH), dB[0] + i * 4096);
    }
    asm volatile("s_waitcnt vmcnt(0)" ::: "memory");
    bar();

#pragma unroll 1
    for (int t = 0; t < 72; t += 2) {
        // step t from buf0, staging t+1 into buf1 (t+1 <= 71 always)
        step32(aBase[0], bBase[0], q2, lane7,
               gA0 + aoff_of(t + 1), gB0 + boff_of(t + 1),
               dA[1], dB[1], true, acc);
        // step t+1 from buf1, staging t+2 into buf0
        step32(aBase[1], bBase[1], q2, lane7,
               gA0 + aoff_of(t + 2), gB0 + boff_of(t + 2),
               dA[0], dB[0], (t + 2 < 72), acc);
    }

    // epilogue: 32x32 C/D layout col=lane&31 (n), row=(r&3)+8*(r>>2)+4*(lane>>5)
#pragma unroll
    for (int j = 0; j < 2; ++j) {
        const int n = n0 + wn * 64 + j * 32 + lane31;
        const float scale = dmod[b * OUT_CH + n] * CONV_COEF;
        const float bv2 = bias[n];
#pragma unroll
        for (int i = 0; i < 4; ++i) {
#pragma unroll
            for (int r = 0; r < 16; ++r) {
                const int m = wm * 128 + i * 32 + (r & 3) + 8 * (r >> 2) + 4 * q2;
                const int h = h0 + (m >> 6);
                const int wq = m & 63;
                out[(((size_t)(b * HWDIM + h)) * HWDIM + wq) * OUT_CH + n] =
                    acc[i][j][r] * scale + bv2;
            }
        }
    }
}

extern "C" void kernel_launch(void* const* d_in, const int* in_sizes, int n_in,
                              void* d_out, int out_size, void* d_ws, size_t ws_size,
                              hipStream_t stream) {
    const float* x    = (const float*)d_in[0];
    const float* wl   = (const float*)d_in[1];
    const float* w    = (const float*)d_in[2];
    const float* bias = (const float*)d_in[3];
    const float* fcw  = (const float*)d_in[4];
    const float* fcb  = (const float*)d_in[5];
    float* out = (float*)d_out;

    char* ws = (char*)d_ws;
    const size_t XS_BYTES = (size_t)BATCH * PADW * PADW * IN_CH * 2;  // 71,368,704
    const size_t WT_BYTES = (size_t)9 * IN_CH * OUT_CH * 2;           //  4,718,592
    ushort* xs   = (ushort*)ws;
    ushort* wT   = (ushort*)(ws + XS_BYTES);
    float*  s    = (float*)(ws + XS_BYTES + WT_BYTES);
    float*  dmod = s + BATCH * IN_CH;
    float*  a2   = dmod + BATCH * OUT_CH;

    k_pre1<<<4400, 256, 0, stream>>>(wl, fcw, fcb, s, w, a2, xs, wT);
    k_pre2<<<32800, 256, 0, stream>>>(x, s, xs, a2, dmod);
    k_conv<<<512, 512, 0, stream>>>(xs, wT, dmod, bias, out);
}